// Round 5
// baseline (415.935 us; speedup 1.0000x reference)
//
#include <hip/hip_runtime.h>
#include <hip/hip_bf16.h>

typedef unsigned short u16;
using bf16x8 = __bf16 __attribute__((ext_vector_type(8)));
using u16x8  = unsigned short __attribute__((ext_vector_type(8)));
using f32x4  = float  __attribute__((ext_vector_type(4)));

#define BB 4
#define TT 4096
#define DD 1024
#define MROWS (BB*TT)   /* 16384 */
#define CT 64           /* scan chunk length */
#define NC (TT/CT)      /* 64 chunks */

__device__ __forceinline__ float sigm(float x) { return 1.0f / (1.0f + __expf(-x)); }
__device__ __forceinline__ u16 f2bf(float f) {
    __hip_bfloat16 h = __float2bfloat16(f);
    return *reinterpret_cast<u16*>(&h);
}
__device__ __forceinline__ float bf2f(u16 u) { return __uint_as_float(((unsigned)u) << 16); }

// async 16B global->LDS (direct-to-shared DMA; LDS dest must be wave-uniform base + lane*16)
__device__ __forceinline__ void async_cp16(const u16* g, u16* l) {
    __builtin_amdgcn_global_load_lds(
        (const __attribute__((address_space(1))) unsigned int*)g,
        (__attribute__((address_space(3))) unsigned int*)l, 16, 0, 0);
}

// ---------------------------------------------------------------- converts
__global__ __launch_bounds__(256) void conv_w4_kernel(const float* __restrict__ w0,
                                                      const float* __restrict__ w1,
                                                      const float* __restrict__ w2,
                                                      const float* __restrict__ w3,
                                                      u16* __restrict__ dst) {
    int i = blockIdx.x * 256 + threadIdx.x;  // 0 .. 4*2^18-1 float4s
    int sel = i >> 18;                       // 2^18 float4 per 1024x1024 weight
    int off = i & 262143;
    const float* s = (sel == 0) ? w0 : (sel == 1) ? w1 : (sel == 2) ? w2 : w3;
    float4 v = *(const float4*)(s + (size_t)off * 4);
    ushort4 u;
    u.x = f2bf(v.x); u.y = f2bf(v.y); u.z = f2bf(v.z); u.w = f2bf(v.w);
    *(ushort4*)(dst + ((size_t)sel << 20) + (size_t)off * 4) = u;
}

// ---------------------------------------------------------------- GEMM 128^2 (proven structure)
// C[m][n] = sum_k A[m][k] * W[n][k], W:[N,K] bf16 row-major.
// AT=float: A is fp32, reg-staged (load float4 before barrier, cvt, ds_write_b128) —
//           fuses the old conv_x into the GEMM (bitwise-identical RN conversion).
// AT=u16:   A is bf16, staged via global_load_lds (proven path).
// LDS XOR-swizzle: physical granule p of row m holds logical k-granule p^(m&7).
// Default blockIdx mapping (XCD chunk-swizzle measured harmful in R3: FETCH 143->232MB).
// 8-phase 256^2 abandoned per R2/R4 A/B: 786/890 TF vs this structure's ~966 TF here
// (1 blk/CU lockstep barriers expose latency; this one gets 2 blk/CU overlap).
#define BM 128
#define BN 128
#define BK 64

template <typename AT, typename OutT>
__global__ __launch_bounds__(256, 2)
void gemm_bt(const AT* __restrict__ Ag, const u16* __restrict__ Bg, int K,
             OutT* __restrict__ P0, OutT* __restrict__ P1, OutT* __restrict__ P2) {
    __shared__ u16 As[BM * BK];
    __shared__ u16 Bs[BN * BK];

    const int tid  = threadIdx.x;
    const int lane = tid & 63;
    const int wid  = tid >> 6;
    const int wm   = wid >> 1;      // wave row 0..1
    const int wn   = wid & 1;       // wave col 0..1
    const int lr   = lane & 15;
    const int lq   = lane >> 4;

    const long bM  = (long)blockIdx.y * BM;
    const long bN0 = (long)blockIdx.x * BN;

    const f32x4 zero = {0.f, 0.f, 0.f, 0.f};
    f32x4 acc[4][4];
#pragma unroll
    for (int i = 0; i < 4; i++)
#pragma unroll
        for (int j = 0; j < 4; j++) acc[i][j] = zero;

    for (int kt = 0; kt < K; kt += BK) {
        float4 afr[4][2];
        if constexpr (sizeof(AT) == 4) {
            // issue A global loads early: latency hides under the pre-stage barrier
#pragma unroll
            for (int j = 0; j < 4; j++) {
                const int G  = j * 256 + tid;
                const int m  = G >> 3;
                const int gk = (G & 7) ^ (m & 7);
                const float* s = (const float*)Ag + (bM + m) * (long)K + kt + gk * 8;
                afr[j][0] = *(const float4*)s;
                afr[j][1] = *(const float4*)(s + 4);
            }
        }
        __syncthreads();
#pragma unroll
        for (int j = 0; j < 4; j++) {
            const int G  = j * 256 + tid;     // LDS granule = wave_base + lane (contiguous)
            const int m  = G >> 3;            // row 0..127
            const int gk = (G & 7) ^ (m & 7); // logical k-granule (swizzle)
            if constexpr (sizeof(AT) == 4) {
                u16x8 wv;
                wv[0] = f2bf(afr[j][0].x); wv[1] = f2bf(afr[j][0].y);
                wv[2] = f2bf(afr[j][0].z); wv[3] = f2bf(afr[j][0].w);
                wv[4] = f2bf(afr[j][1].x); wv[5] = f2bf(afr[j][1].y);
                wv[6] = f2bf(afr[j][1].z); wv[7] = f2bf(afr[j][1].w);
                *(u16x8*)(&As[G * 8]) = wv;   // one ds_write_b128
            } else {
                async_cp16((const u16*)Ag + (bM + m) * (long)K + kt + gk * 8, &As[G * 8]);
            }
            async_cp16(Bg + (bN0 + m) * K + kt + gk * 8, &Bs[G * 8]);
        }
        __syncthreads();   // compiler emits s_waitcnt vmcnt(0) lgkmcnt(0) before s_barrier
#pragma unroll
        for (int kk = 0; kk < BK / 32; kk++) {
            bf16x8 av[4], bv[4];
#pragma unroll
            for (int f = 0; f < 4; f++) {
                const int am = wm * 64 + f * 16 + lr;
                const int ag = (kk * 4 + lq) ^ (am & 7);
                av[f] = *(const bf16x8*)(&As[am * 64 + ag * 8]);
                const int bn = wn * 64 + f * 16 + lr;
                const int bg = (kk * 4 + lq) ^ (bn & 7);
                bv[f] = *(const bf16x8*)(&Bs[bn * 64 + bg * 8]);
            }
#pragma unroll
            for (int i = 0; i < 4; i++)
#pragma unroll
                for (int j = 0; j < 4; j++)
                    acc[i][j] = __builtin_amdgcn_mfma_f32_16x16x32_bf16(av[i], bv[j],
                                                                        acc[i][j], 0, 0, 0);
        }
    }

    const int pl = (int)(bN0 >> 10);   // BN=128 divides 1024 -> whole block in one plane
    OutT* P = (pl == 0) ? P0 : ((pl == 1) ? P1 : P2);
    const int cn = (int)(bN0 & 1023);
#pragma unroll
    for (int i = 0; i < 4; i++) {
        const long m0 = bM + wm * 64 + i * 16 + lq * 4;
#pragma unroll
        for (int j = 0; j < 4; j++) {
            const int n = cn + wn * 64 + j * 16 + lr;
#pragma unroll
            for (int r = 0; r < 4; r++) {
                if constexpr (sizeof(OutT) == 2)
                    P[(m0 + r) * 1024 + n] = f2bf(acc[i][j][r]);
                else
                    P[(m0 + r) * 1024 + n] = acc[i][j][r];
            }
        }
    }
}

// ---------------------------------------------------------------- chunked scan
// h_t = f_t * h_{t-1} + silu(i_t)*(1-f_t),  f = sigmoid(f_pre); planes are bf16
__global__ __launch_bounds__(256) void scan_pass1(const u16* __restrict__ ip,
                                                  const u16* __restrict__ fp,
                                                  float* __restrict__ Fc,
                                                  float* __restrict__ Ic) {
    const int tid = blockIdx.x * 256 + threadIdx.x;  // B*NC*D/4 = 65536 threads
    const int d4  = tid & 255;
    const int c   = (tid >> 8) & (NC - 1);
    const int b   = tid >> 14;
    size_t base = ((size_t)(b * TT + c * CT) << 10) + (size_t)d4 * 4;
    float F[4] = {1.f, 1.f, 1.f, 1.f};
    float I[4] = {0.f, 0.f, 0.f, 0.f};
#pragma unroll 8
    for (int t = 0; t < CT; t++) {
        ushort4 fu = *(const ushort4*)(fp + base);
        ushort4 iu = *(const ushort4*)(ip + base);
        base += DD;
        const u16 fa[4] = {fu.x, fu.y, fu.z, fu.w};
        const u16 ia[4] = {iu.x, iu.y, iu.z, iu.w};
#pragma unroll
        for (int j = 0; j < 4; j++) {
            float f  = sigm(bf2f(fa[j]));
            float iv = bf2f(ia[j]);
            float v  = iv * sigm(iv) * (1.f - f);
            I[j] = fmaf(f, I[j], v);
            F[j] *= f;
        }
    }
    const size_t o = (((size_t)(b * NC + c)) << 10) + (size_t)d4 * 4;
    float4 vF = {F[0], F[1], F[2], F[3]};
    float4 vI = {I[0], I[1], I[2], I[3]};
    *(float4*)(Fc + o) = vF;
    *(float4*)(Ic + o) = vI;
}

// pass2: exclusive scan over the 64 chunks via in-wave Kogge-Stone.
__global__ __launch_bounds__(256) void scan_pass2(const float* __restrict__ Fc,
                                                  const float* __restrict__ Ic,
                                                  float* __restrict__ Hin) {
    const int gtid = blockIdx.x * 256 + threadIdx.x;   // B*D*64 = 262144 threads
    const int lane = gtid & 63;                        // chunk c
    const int w    = gtid >> 6;                        // wave id = (b,d)
    const int b    = w >> 10;
    const int d    = w & 1023;
    const int idx  = ((b * NC + lane) << 10) + d;
    float F = Fc[idx];
    float I = Ic[idx];
#pragma unroll
    for (int s = 1; s < 64; s <<= 1) {
        float Fp = __shfl_up(F, s, 64);
        float Ip = __shfl_up(I, s, 64);
        if (lane >= s) {
            I = fmaf(Ip, F, I);
            F *= Fp;
        }
    }
    float Hex = __shfl_up(I, 1, 64);
    if (lane == 0) Hex = 0.f;
    Hin[idx] = Hex;
}

// pass3 fused with RMSNorm*swish(g), ONE barrier total (R3's version had 64 — its
// failure mode). Block = one (b,chunk), full D (256 thr x 4 d).
// Scan loop: compute h fp32, stash bf16 h in a 128KB LDS plane, wave-shfl-reduce
// sum(h^2), lane0 -> sw[wave][t] (no block barrier). One __syncthreads. Epilogue:
// tot[t] via 4 broadcast LDS reads, read g, write o. Saves the h HBM round-trip.
__global__ __launch_bounds__(256) void scan3_norm(const u16* __restrict__ ip,
                                                  const u16* __restrict__ fp,
                                                  const float* __restrict__ Hin,
                                                  const u16* __restrict__ gp,
                                                  const float* __restrict__ w,
                                                  u16* __restrict__ oout) {
    __shared__ u16 hlds[CT * DD];     // [64 t][1024 d] bf16 = 128 KB
    __shared__ float sw[4][CT];       // per-wave partial sums, 1 KB
    const int t_   = threadIdx.x;     // d4 index
    const int lane = t_ & 63;
    const int wv_  = t_ >> 6;
    const int c    = blockIdx.x & (NC - 1);
    const int b    = blockIdx.x >> 6;
    size_t base = ((size_t)(b * TT + c * CT) << 10) + (size_t)t_ * 4;
    const size_t o = (((size_t)(b * NC + c)) << 10) + (size_t)t_ * 4;
    float4 hv = *(const float4*)(Hin + o);
    float h[4] = {hv.x, hv.y, hv.z, hv.w};
    size_t rb = base;
#pragma unroll 4
    for (int t = 0; t < CT; t++) {
        ushort4 fu = *(const ushort4*)(fp + rb);
        ushort4 iu = *(const ushort4*)(ip + rb);
        rb += DD;
        const u16 fa[4] = {fu.x, fu.y, fu.z, fu.w};
        const u16 ia[4] = {iu.x, iu.y, iu.z, iu.w};
        float ss = 0.f;
        ushort4 hu;
        u16 ha[4];
#pragma unroll
        for (int j = 0; j < 4; j++) {
            float f  = sigm(bf2f(fa[j]));
            float iv = bf2f(ia[j]);
            float v  = iv * sigm(iv) * (1.f - f);
            h[j] = fmaf(f, h[j], v);
            ss = fmaf(h[j], h[j], ss);
            ha[j] = f2bf(h[j]);
        }
        hu.x = ha[0]; hu.y = ha[1]; hu.z = ha[2]; hu.w = ha[3];
        *(ushort4*)(&hlds[t * DD + t_ * 4]) = hu;   // b64, 2-way (free)
#pragma unroll
        for (int off = 32; off > 0; off >>= 1) ss += __shfl_down(ss, off);
        if (lane == 0) sw[wv_][t] = ss;
    }
    __syncthreads();
    const float4 wvv = *(const float4*)(w + (size_t)t_ * 4);
    const float wl[4] = {wvv.x, wvv.y, wvv.z, wvv.w};
    size_t wb = base;
#pragma unroll 4
    for (int t = 0; t < CT; t++) {
        const float tot = sw[0][t] + sw[1][t] + sw[2][t] + sw[3][t];
        const float rms = rsqrtf(tot * (1.f / 1024.f) + 1e-5f);
        ushort4 hu = *(const ushort4*)(&hlds[t * DD + t_ * 4]);
        ushort4 gu = *(const ushort4*)(gp + wb);
        const u16 ha[4] = {hu.x, hu.y, hu.z, hu.w};
        const u16 ga[4] = {gu.x, gu.y, gu.z, gu.w};
        ushort4 ou;
        u16 oa[4];
#pragma unroll
        for (int j = 0; j < 4; j++) {
            float gv = bf2f(ga[j]);
            oa[j] = f2bf(bf2f(ha[j]) * rms * wl[j] * gv * sigm(gv));
        }
        ou.x = oa[0]; ou.y = oa[1]; ou.z = oa[2]; ou.w = oa[3];
        *(ushort4*)(oout + wb) = ou;
        wb += DD;
    }
}

// ---------------------------------------------------------------- launch
extern "C" void kernel_launch(void* const* d_in, const int* in_sizes, int n_in,
                              void* d_out, int out_size, void* d_ws, size_t ws_size,
                              hipStream_t stream) {
    const float* x  = (const float*)d_in[0];
    const float* Wi = (const float*)d_in[1];
    const float* Wf = (const float*)d_in[2];
    const float* Wg = (const float*)d_in[3];
    const float* Wo = (const float*)d_in[4];
    const float* nw = (const float*)d_in[5];
    float* out = (float*)d_out;

    const size_t MB = 1ull << 20;
    char* ws = (char*)d_ws;
    u16*   ob  = (u16*)(ws);              // 32MB: o bf16 (gated-norm output)
    u16*   Wb  = (u16*)(ws + 32 * MB);    // 8MB: [Wi;Wf;Wg;Wo] bf16, K-major rows
    u16*   Pi  = (u16*)(ws + 40 * MB);    // 32MB: i_pre bf16
    u16*   Pf  = (u16*)(ws + 72 * MB);    // 32MB: f_pre bf16
    float* Fc  = (float*)(ws + 104 * MB); // 1MB
    float* Ic  = Fc + BB * NC * DD;       // 1MB
    float* Hin = Ic + BB * NC * DD;       // 1MB
    u16*   g   = (u16*)d_out;             // g plane (bf16) parked in d_out until final GEMM

    conv_w4_kernel<<<4096, 256, 0, stream>>>(Wi, Wf, Wg, Wo, Wb);
    // i_pre / f_pre / g in one GEMM: N=3072; A = x fp32, converted in-kernel (conv_x fused)
    gemm_bt<float, u16><<<dim3(24, 128), 256, 0, stream>>>(x, Wb, 1024, Pi, Pf, g);
    scan_pass1<<<256, 256, 0, stream>>>(Pi, Pf, Fc, Ic);
    scan_pass2<<<1024, 256, 0, stream>>>(Fc, Ic, Hin);
    // fused scan finish + RMSNorm*swish(g), single barrier: writes o into ob
    scan3_norm<<<256, 256, 0, stream>>>(Pi, Pf, Hin, g, nw, ob);
    // out = o @ Wo^T
    gemm_bt<u16, float><<<dim3(8, 128), 256, 0, stream>>>(ob, Wb + 3ull * 1024 * 1024, 1024,
                                                          out, out, out);
}

// Round 6
// 388.655 us; speedup vs baseline: 1.0702x; 1.0702x over previous
//
#include <hip/hip_runtime.h>
#include <hip/hip_bf16.h>

typedef unsigned short u16;
using bf16x8 = __bf16 __attribute__((ext_vector_type(8)));
using f32x4  = float  __attribute__((ext_vector_type(4)));

#define BB 4
#define TT 4096
#define DD 1024
#define MROWS (BB*TT)   /* 16384 */
#define CT 64           /* scan chunk length */
#define NC (TT/CT)      /* 64 chunks */

__device__ __forceinline__ float sigm(float x) { return 1.0f / (1.0f + __expf(-x)); }
__device__ __forceinline__ u16 f2bf(float f) {
    __hip_bfloat16 h = __float2bfloat16(f);
    return *reinterpret_cast<u16*>(&h);
}
__device__ __forceinline__ float bf2f(u16 u) { return __uint_as_float(((unsigned)u) << 16); }

// async 16B global->LDS (direct-to-shared DMA; LDS dest must be wave-uniform base + lane*16)
__device__ __forceinline__ void async_cp16(const u16* g, u16* l) {
    __builtin_amdgcn_global_load_lds(
        (const __attribute__((address_space(1))) unsigned int*)g,
        (__attribute__((address_space(3))) unsigned int*)l, 16, 0, 0);
}

// ---------------------------------------------------------------- converts
__global__ __launch_bounds__(256) void conv_x_kernel(const float* __restrict__ s,
                                                     u16* __restrict__ d) {
    size_t i = (size_t)blockIdx.x * 256 + threadIdx.x;   // one float4 per thread
    float4 v = *(const float4*)(s + i * 4);
    ushort4 u;
    u.x = f2bf(v.x); u.y = f2bf(v.y); u.z = f2bf(v.z); u.w = f2bf(v.w);
    *(ushort4*)(d + i * 4) = u;
}

__global__ __launch_bounds__(256) void conv_w4_kernel(const float* __restrict__ w0,
                                                      const float* __restrict__ w1,
                                                      const float* __restrict__ w2,
                                                      const float* __restrict__ w3,
                                                      u16* __restrict__ dst) {
    int i = blockIdx.x * 256 + threadIdx.x;  // 0 .. 4*2^18-1 float4s
    int sel = i >> 18;                       // 2^18 float4 per 1024x1024 weight
    int off = i & 262143;
    const float* s = (sel == 0) ? w0 : (sel == 1) ? w1 : (sel == 2) ? w2 : w3;
    float4 v = *(const float4*)(s + (size_t)off * 4);
    ushort4 u;
    u.x = f2bf(v.x); u.y = f2bf(v.y); u.z = f2bf(v.z); u.w = f2bf(v.w);
    *(ushort4*)(dst + ((size_t)sel << 20) + (size_t)off * 4) = u;
}

// ---------------------------------------------------------------- GEMM 128^2 (proven, r0 config)
// C[m][n] = sum_k A[m][k] * W[n][k], A:[M,K] bf16 row-major, W:[N,K] bf16 row-major.
// 128x128 tile, BK=64, 4 waves (2x2), each wave 64x64 via 4x4 mfma_f32_16x16x32_bf16.
// Both operands staged via global_load_lds (deep prefetch queue retiring at the barrier).
// LDS XOR-swizzle on the GLOBAL address side; 0 bank conflicts measured.
// Measured A/B history: XCD chunk-swizzle harmful (R3: FETCH 143->232MB); 256^2 8-phase
// harmful (R2/R4: 786/890 TF vs this ~966 TF — 1 blk/CU lockstep barriers); fp32-A
// reg-staging harmful (R5: 158us, raw HBM latency on the K-step critical path).
#define BM 128
#define BN 128
#define BK 64

template <typename OutT>
__global__ __launch_bounds__(256, 2)
void gemm_bf16_bt(const u16* __restrict__ Ag, const u16* __restrict__ Bg, int K,
                  OutT* __restrict__ P0, OutT* __restrict__ P1, OutT* __restrict__ P2) {
    __shared__ u16 As[BM * BK];
    __shared__ u16 Bs[BN * BK];

    const int tid  = threadIdx.x;
    const int lane = tid & 63;
    const int wid  = tid >> 6;
    const int wm   = wid >> 1;      // wave row 0..1
    const int wn   = wid & 1;       // wave col 0..1
    const int lr   = lane & 15;
    const int lq   = lane >> 4;

    const long bM  = (long)blockIdx.y * BM;
    const long bN0 = (long)blockIdx.x * BN;

    const f32x4 zero = {0.f, 0.f, 0.f, 0.f};
    f32x4 acc[4][4];
#pragma unroll
    for (int i = 0; i < 4; i++)
#pragma unroll
        for (int j = 0; j < 4; j++) acc[i][j] = zero;

    for (int kt = 0; kt < K; kt += BK) {
        __syncthreads();
#pragma unroll
        for (int j = 0; j < 4; j++) {
            const int G  = j * 256 + tid;     // LDS granule = wave_base + lane (contiguous)
            const int m  = G >> 3;            // row 0..127
            const int p  = G & 7;             // physical granule
            const int gk = p ^ (m & 7);       // logical k-granule (swizzle on global side)
            async_cp16(Ag + (bM + m) * K + kt + gk * 8, &As[G * 8]);
            async_cp16(Bg + (bN0 + m) * K + kt + gk * 8, &Bs[G * 8]);
        }
        __syncthreads();   // compiler emits s_waitcnt vmcnt(0) before s_barrier
#pragma unroll
        for (int kk = 0; kk < BK / 32; kk++) {
            bf16x8 av[4], bv[4];
#pragma unroll
            for (int f = 0; f < 4; f++) {
                const int am = wm * 64 + f * 16 + lr;
                const int ag = (kk * 4 + lq) ^ (am & 7);
                av[f] = *(const bf16x8*)(&As[am * 64 + ag * 8]);
                const int bn = wn * 64 + f * 16 + lr;
                const int bg = (kk * 4 + lq) ^ (bn & 7);
                bv[f] = *(const bf16x8*)(&Bs[bn * 64 + bg * 8]);
            }
#pragma unroll
            for (int i = 0; i < 4; i++)
#pragma unroll
                for (int j = 0; j < 4; j++)
                    acc[i][j] = __builtin_amdgcn_mfma_f32_16x16x32_bf16(av[i], bv[j],
                                                                        acc[i][j], 0, 0, 0);
        }
    }

    const int pl = (int)(bN0 >> 10);   // BN=128 divides 1024 -> whole block in one plane
    OutT* P = (pl == 0) ? P0 : ((pl == 1) ? P1 : P2);
    const int cn = (int)(bN0 & 1023);
#pragma unroll
    for (int i = 0; i < 4; i++) {
        const long m0 = bM + wm * 64 + i * 16 + lq * 4;
#pragma unroll
        for (int j = 0; j < 4; j++) {
            const int n = cn + wn * 64 + j * 16 + lr;
#pragma unroll
            for (int r = 0; r < 4; r++) {
                if constexpr (sizeof(OutT) == 2)
                    P[(m0 + r) * 1024 + n] = f2bf(acc[i][j][r]);
                else
                    P[(m0 + r) * 1024 + n] = acc[i][j][r];
            }
        }
    }
}

// ---------------------------------------------------------------- chunked scan
// h_t = f_t * h_{t-1} + silu(i_t)*(1-f_t),  f = sigmoid(f_pre); planes are bf16
__global__ __launch_bounds__(256) void scan_pass1(const u16* __restrict__ ip,
                                                  const u16* __restrict__ fp,
                                                  float* __restrict__ Fc,
                                                  float* __restrict__ Ic) {
    const int tid = blockIdx.x * 256 + threadIdx.x;  // B*NC*D/4 = 65536 threads
    const int d4  = tid & 255;
    const int c   = (tid >> 8) & (NC - 1);
    const int b   = tid >> 14;
    size_t base = ((size_t)(b * TT + c * CT) << 10) + (size_t)d4 * 4;
    float F[4] = {1.f, 1.f, 1.f, 1.f};
    float I[4] = {0.f, 0.f, 0.f, 0.f};
#pragma unroll 8
    for (int t = 0; t < CT; t++) {
        ushort4 fu = *(const ushort4*)(fp + base);
        ushort4 iu = *(const ushort4*)(ip + base);
        base += DD;
        const u16 fa[4] = {fu.x, fu.y, fu.z, fu.w};
        const u16 ia[4] = {iu.x, iu.y, iu.z, iu.w};
#pragma unroll
        for (int j = 0; j < 4; j++) {
            float f  = sigm(bf2f(fa[j]));
            float iv = bf2f(ia[j]);
            float v  = iv * sigm(iv) * (1.f - f);
            I[j] = fmaf(f, I[j], v);
            F[j] *= f;
        }
    }
    const size_t o = (((size_t)(b * NC + c)) << 10) + (size_t)d4 * 4;
    float4 vF = {F[0], F[1], F[2], F[3]};
    float4 vI = {I[0], I[1], I[2], I[3]};
    *(float4*)(Fc + o) = vF;
    *(float4*)(Ic + o) = vI;
}

// pass2: exclusive scan over the 64 chunks via in-wave Kogge-Stone.
__global__ __launch_bounds__(256) void scan_pass2(const float* __restrict__ Fc,
                                                  const float* __restrict__ Ic,
                                                  float* __restrict__ Hin) {
    const int gtid = blockIdx.x * 256 + threadIdx.x;   // B*D*64 = 262144 threads
    const int lane = gtid & 63;                        // chunk c
    const int w    = gtid >> 6;                        // wave id = (b,d)
    const int b    = w >> 10;
    const int d    = w & 1023;
    const int idx  = ((b * NC + lane) << 10) + d;
    float F = Fc[idx];
    float I = Ic[idx];
#pragma unroll
    for (int s = 1; s < 64; s <<= 1) {
        float Fp = __shfl_up(F, s, 64);
        float Ip = __shfl_up(I, s, 64);
        if (lane >= s) {
            I = fmaf(Ip, F, I);
            F *= Fp;
        }
    }
    float Hex = __shfl_up(I, 1, 64);
    if (lane == 0) Hex = 0.f;
    Hin[idx] = Hex;
}

// pass3 fused with RMSNorm*swish(g), ONE barrier total. Block = one (b,chunk),
// full D (256 thr x 4 d). Scan loop: compute h fp32, stash bf16 h in a 128KB LDS
// plane, wave-shfl-reduce sum(h^2), lane0 -> sw[wave][t] (no block barrier).
// One __syncthreads. Epilogue: tot[t] via 4 broadcast LDS reads, read g, write o.
// Saves the h HBM round-trip (64MB) + one launch vs separate scan3 + rmsnorm.
__global__ __launch_bounds__(256) void scan3_norm(const u16* __restrict__ ip,
                                                  const u16* __restrict__ fp,
                                                  const float* __restrict__ Hin,
                                                  const u16* __restrict__ gp,
                                                  const float* __restrict__ w,
                                                  u16* __restrict__ oout) {
    __shared__ u16 hlds[CT * DD];     // [64 t][1024 d] bf16 = 128 KB
    __shared__ float sw[4][CT];       // per-wave partial sums, 1 KB
    const int t_   = threadIdx.x;     // d4 index
    const int lane = t_ & 63;
    const int wv_  = t_ >> 6;
    const int c    = blockIdx.x & (NC - 1);
    const int b    = blockIdx.x >> 6;
    size_t base = ((size_t)(b * TT + c * CT) << 10) + (size_t)t_ * 4;
    const size_t o = (((size_t)(b * NC + c)) << 10) + (size_t)t_ * 4;
    float4 hv = *(const float4*)(Hin + o);
    float h[4] = {hv.x, hv.y, hv.z, hv.w};
    size_t rb = base;
#pragma unroll 4
    for (int t = 0; t < CT; t++) {
        ushort4 fu = *(const ushort4*)(fp + rb);
        ushort4 iu = *(const ushort4*)(ip + rb);
        rb += DD;
        const u16 fa[4] = {fu.x, fu.y, fu.z, fu.w};
        const u16 ia[4] = {iu.x, iu.y, iu.z, iu.w};
        float ss = 0.f;
        ushort4 hu;
        u16 ha[4];
#pragma unroll
        for (int j = 0; j < 4; j++) {
            float f  = sigm(bf2f(fa[j]));
            float iv = bf2f(ia[j]);
            float v  = iv * sigm(iv) * (1.f - f);
            h[j] = fmaf(f, h[j], v);
            ss = fmaf(h[j], h[j], ss);
            ha[j] = f2bf(h[j]);
        }
        hu.x = ha[0]; hu.y = ha[1]; hu.z = ha[2]; hu.w = ha[3];
        *(ushort4*)(&hlds[t * DD + t_ * 4]) = hu;   // b64, 2-way (free)
#pragma unroll
        for (int off = 32; off > 0; off >>= 1) ss += __shfl_down(ss, off);
        if (lane == 0) sw[wv_][t] = ss;
    }
    __syncthreads();
    const float4 wvv = *(const float4*)(w + (size_t)t_ * 4);
    const float wl[4] = {wvv.x, wvv.y, wvv.z, wvv.w};
    size_t wb = base;
#pragma unroll 4
    for (int t = 0; t < CT; t++) {
        const float tot = sw[0][t] + sw[1][t] + sw[2][t] + sw[3][t];
        const float rms = rsqrtf(tot * (1.f / 1024.f) + 1e-5f);
        ushort4 hu = *(const ushort4*)(&hlds[t * DD + t_ * 4]);
        ushort4 gu = *(const ushort4*)(gp + wb);
        const u16 ha[4] = {hu.x, hu.y, hu.z, hu.w};
        const u16 ga[4] = {gu.x, gu.y, gu.z, gu.w};
        ushort4 ou;
        u16 oa[4];
#pragma unroll
        for (int j = 0; j < 4; j++) {
            float gv = bf2f(ga[j]);
            oa[j] = f2bf(bf2f(ha[j]) * rms * wl[j] * gv * sigm(gv));
        }
        ou.x = oa[0]; ou.y = oa[1]; ou.z = oa[2]; ou.w = oa[3];
        *(ushort4*)(oout + wb) = ou;
        wb += DD;
    }
}

// ---------------------------------------------------------------- launch
extern "C" void kernel_launch(void* const* d_in, const int* in_sizes, int n_in,
                              void* d_out, int out_size, void* d_ws, size_t ws_size,
                              hipStream_t stream) {
    const float* x  = (const float*)d_in[0];
    const float* Wi = (const float*)d_in[1];
    const float* Wf = (const float*)d_in[2];
    const float* Wg = (const float*)d_in[3];
    const float* Wo = (const float*)d_in[4];
    const float* nw = (const float*)d_in[5];
    float* out = (float*)d_out;

    const size_t MB = 1ull << 20;
    char* ws = (char*)d_ws;
    u16*   xo  = (u16*)(ws);              // 32MB: x_bf16, later o_bf16
    u16*   Wb  = (u16*)(ws + 32 * MB);    // 8MB: [Wi;Wf;Wg;Wo] bf16, K-major rows
    u16*   Pi  = (u16*)(ws + 40 * MB);    // 32MB: i_pre bf16
    u16*   Pf  = (u16*)(ws + 72 * MB);    // 32MB: f_pre bf16
    float* Fc  = (float*)(ws + 104 * MB); // 1MB
    float* Ic  = Fc + BB * NC * DD;       // 1MB
    float* Hin = Ic + BB * NC * DD;       // 1MB
    u16*   g   = (u16*)d_out;             // g plane (bf16) parked in d_out until final GEMM

    conv_x_kernel<<<16384, 256, 0, stream>>>(x, xo);
    conv_w4_kernel<<<4096, 256, 0, stream>>>(Wi, Wf, Wg, Wo, Wb);
    // i_pre / f_pre / g in one GEMM: N=3072
    gemm_bf16_bt<u16><<<dim3(24, 128), 256, 0, stream>>>(xo, Wb, 1024, Pi, Pf, g);
    scan_pass1<<<256, 256, 0, stream>>>(Pi, Pf, Fc, Ic);
    scan_pass2<<<1024, 256, 0, stream>>>(Fc, Ic, Hin);
    // fused scan finish + RMSNorm*swish(g), single barrier: writes o into xo
    scan3_norm<<<256, 256, 0, stream>>>(Pi, Pf, Hin, g, nw, xo);
    // out = o @ Wo^T
    gemm_bf16_bt<float><<<dim3(8, 128), 256, 0, stream>>>(xo, Wb + 3ull * 1024 * 1024, 1024,
                                                          out, out, out);
}

// Round 7
// 350.507 us; speedup vs baseline: 1.1867x; 1.1088x over previous
//
#include <hip/hip_runtime.h>
#include <hip/hip_bf16.h>

typedef unsigned short u16;
using bf16x8 = __bf16 __attribute__((ext_vector_type(8)));
using f32x4  = float  __attribute__((ext_vector_type(4)));

#define BB 4
#define TT 4096
#define DD 1024
#define MROWS (BB*TT)   /* 16384 */
#define CT 16           /* scan chunk length (16 -> 4x thread-level parallelism) */
#define NC (TT/CT)      /* 256 chunks */

__device__ __forceinline__ float sigm(float x) { return 1.0f / (1.0f + __expf(-x)); }
__device__ __forceinline__ u16 f2bf(float f) {
    __hip_bfloat16 h = __float2bfloat16(f);
    return *reinterpret_cast<u16*>(&h);
}
__device__ __forceinline__ float bf2f(u16 u) { return __uint_as_float(((unsigned)u) << 16); }

// async 16B global->LDS (direct-to-shared DMA; LDS dest must be wave-uniform base + lane*16)
__device__ __forceinline__ void async_cp16(const u16* g, u16* l) {
    __builtin_amdgcn_global_load_lds(
        (const __attribute__((address_space(1))) unsigned int*)g,
        (__attribute__((address_space(3))) unsigned int*)l, 16, 0, 0);
}

// ---------------------------------------------------------------- converts
__global__ __launch_bounds__(256) void conv_x_kernel(const float* __restrict__ s,
                                                     u16* __restrict__ d) {
    size_t i = (size_t)blockIdx.x * 256 + threadIdx.x;   // one float4 per thread
    float4 v = *(const float4*)(s + i * 4);
    ushort4 u;
    u.x = f2bf(v.x); u.y = f2bf(v.y); u.z = f2bf(v.z); u.w = f2bf(v.w);
    *(ushort4*)(d + i * 4) = u;
}

__global__ __launch_bounds__(256) void conv_w4_kernel(const float* __restrict__ w0,
                                                      const float* __restrict__ w1,
                                                      const float* __restrict__ w2,
                                                      const float* __restrict__ w3,
                                                      u16* __restrict__ dst) {
    int i = blockIdx.x * 256 + threadIdx.x;  // 0 .. 4*2^18-1 float4s
    int sel = i >> 18;                       // 2^18 float4 per 1024x1024 weight
    int off = i & 262143;
    const float* s = (sel == 0) ? w0 : (sel == 1) ? w1 : (sel == 2) ? w2 : w3;
    float4 v = *(const float4*)(s + (size_t)off * 4);
    ushort4 u;
    u.x = f2bf(v.x); u.y = f2bf(v.y); u.z = f2bf(v.z); u.w = f2bf(v.w);
    *(ushort4*)(dst + ((size_t)sel << 20) + (size_t)off * 4) = u;
}

// ---------------------------------------------------------------- GEMM 128^2 (proven, r0 config)
// C[m][n] = sum_k A[m][k] * W[n][k], A:[M,K] bf16 row-major, W:[N,K] bf16 row-major.
// 128x128 tile, BK=64, 4 waves (2x2), each wave 64x64 via 4x4 mfma_f32_16x16x32_bf16.
// Both operands staged via global_load_lds (deep prefetch queue retiring at the barrier).
// LDS XOR-swizzle on the GLOBAL address side; 0 bank conflicts measured.
// Measured A/B history: XCD chunk-swizzle harmful (R3: FETCH 143->232MB); 256^2 8-phase
// harmful (R2/R4: 786/890 TF vs this ~966 TF — 1 blk/CU lockstep barriers); fp32-A
// reg-staging harmful (R5: 158us, raw HBM latency on the K-step critical path).
#define BM 128
#define BN 128
#define BK 64

template <typename OutT>
__global__ __launch_bounds__(256, 2)
void gemm_bf16_bt(const u16* __restrict__ Ag, const u16* __restrict__ Bg, int K,
                  OutT* __restrict__ P0, OutT* __restrict__ P1, OutT* __restrict__ P2) {
    __shared__ u16 As[BM * BK];
    __shared__ u16 Bs[BN * BK];

    const int tid  = threadIdx.x;
    const int lane = tid & 63;
    const int wid  = tid >> 6;
    const int wm   = wid >> 1;      // wave row 0..1
    const int wn   = wid & 1;       // wave col 0..1
    const int lr   = lane & 15;
    const int lq   = lane >> 4;

    const long bM  = (long)blockIdx.y * BM;
    const long bN0 = (long)blockIdx.x * BN;

    const f32x4 zero = {0.f, 0.f, 0.f, 0.f};
    f32x4 acc[4][4];
#pragma unroll
    for (int i = 0; i < 4; i++)
#pragma unroll
        for (int j = 0; j < 4; j++) acc[i][j] = zero;

    for (int kt = 0; kt < K; kt += BK) {
        __syncthreads();
#pragma unroll
        for (int j = 0; j < 4; j++) {
            const int G  = j * 256 + tid;     // LDS granule = wave_base + lane (contiguous)
            const int m  = G >> 3;            // row 0..127
            const int p  = G & 7;             // physical granule
            const int gk = p ^ (m & 7);       // logical k-granule (swizzle on global side)
            async_cp16(Ag + (bM + m) * K + kt + gk * 8, &As[G * 8]);
            async_cp16(Bg + (bN0 + m) * K + kt + gk * 8, &Bs[G * 8]);
        }
        __syncthreads();   // compiler emits s_waitcnt vmcnt(0) before s_barrier
#pragma unroll
        for (int kk = 0; kk < BK / 32; kk++) {
            bf16x8 av[4], bv[4];
#pragma unroll
            for (int f = 0; f < 4; f++) {
                const int am = wm * 64 + f * 16 + lr;
                const int ag = (kk * 4 + lq) ^ (am & 7);
                av[f] = *(const bf16x8*)(&As[am * 64 + ag * 8]);
                const int bn = wn * 64 + f * 16 + lr;
                const int bg = (kk * 4 + lq) ^ (bn & 7);
                bv[f] = *(const bf16x8*)(&Bs[bn * 64 + bg * 8]);
            }
#pragma unroll
            for (int i = 0; i < 4; i++)
#pragma unroll
                for (int j = 0; j < 4; j++)
                    acc[i][j] = __builtin_amdgcn_mfma_f32_16x16x32_bf16(av[i], bv[j],
                                                                        acc[i][j], 0, 0, 0);
        }
    }

    const int pl = (int)(bN0 >> 10);   // BN=128 divides 1024 -> whole block in one plane
    OutT* P = (pl == 0) ? P0 : ((pl == 1) ? P1 : P2);
    const int cn = (int)(bN0 & 1023);
#pragma unroll
    for (int i = 0; i < 4; i++) {
        const long m0 = bM + wm * 64 + i * 16 + lq * 4;
#pragma unroll
        for (int j = 0; j < 4; j++) {
            const int n = cn + wn * 64 + j * 16 + lr;
#pragma unroll
            for (int r = 0; r < 4; r++) {
                if constexpr (sizeof(OutT) == 2)
                    P[(m0 + r) * 1024 + n] = f2bf(acc[i][j][r]);
                else
                    P[(m0 + r) * 1024 + n] = acc[i][j][r];
            }
        }
    }
}

// ---------------------------------------------------------------- chunked scan (CT=16)
// h_t = f_t * h_{t-1} + silu(i_t)*(1-f_t),  f = sigmoid(f_pre); planes are bf16.
// CT=16 -> 262144 threads in pass1/pass3 (1024 blocks): ~67MB issuable in flight vs
// ~8MB at CT=64 (Little's law: ~10MB needed for 6.3TB/s; CT=64 ran latency-starved).
__global__ __launch_bounds__(256) void scan_pass1(const u16* __restrict__ ip,
                                                  const u16* __restrict__ fp,
                                                  float* __restrict__ Fc,
                                                  float* __restrict__ Ic) {
    const int tid = blockIdx.x * 256 + threadIdx.x;  // B*NC*D/4 = 262144 threads
    const int d4  = tid & 255;                       // d/4
    const int c   = (tid >> 8) & (NC - 1);
    const int b   = tid >> 16;
    size_t base = ((size_t)(b * TT + c * CT) << 10) + (size_t)d4 * 4;
    float F[4] = {1.f, 1.f, 1.f, 1.f};
    float I[4] = {0.f, 0.f, 0.f, 0.f};
#pragma unroll
    for (int t = 0; t < CT; t++) {
        ushort4 fu = *(const ushort4*)(fp + base);
        ushort4 iu = *(const ushort4*)(ip + base);
        base += DD;
        const u16 fa[4] = {fu.x, fu.y, fu.z, fu.w};
        const u16 ia[4] = {iu.x, iu.y, iu.z, iu.w};
#pragma unroll
        for (int j = 0; j < 4; j++) {
            float f  = sigm(bf2f(fa[j]));
            float iv = bf2f(ia[j]);
            float v  = iv * sigm(iv) * (1.f - f);
            I[j] = fmaf(f, I[j], v);
            F[j] *= f;
        }
    }
    const size_t o = (((size_t)(b * NC + c)) << 10) + (size_t)d4 * 4;
    float4 vF = {F[0], F[1], F[2], F[3]};
    float4 vI = {I[0], I[1], I[2], I[3]};
    *(float4*)(Fc + o) = vF;
    *(float4*)(Ic + o) = vI;
}

// pass2: exclusive scan over NC=256 chunks, wave per (b,d): 4 segments of 64 lanes,
// Kogge-Stone inclusive within segment, scalar I-carry across segments (only the
// I-component of the running aggregate feeds Hin / the next segment).
__global__ __launch_bounds__(256) void scan_pass2(const float* __restrict__ Fc,
                                                  const float* __restrict__ Ic,
                                                  float* __restrict__ Hin) {
    const int gtid = blockIdx.x * 256 + threadIdx.x;   // B*D*64 = 262144 threads
    const int lane = gtid & 63;
    const int w    = gtid >> 6;                        // wave id = (b,d)
    const int b    = w >> 10;
    const int d    = w & 1023;
    float carryI = 0.f;                                // h entering current segment
#pragma unroll
    for (int seg = 0; seg < NC / 64; seg++) {
        const int c   = seg * 64 + lane;
        const int idx = ((b * NC + c) << 10) + d;
        float F = Fc[idx];
        float I = Ic[idx];
#pragma unroll
        for (int s = 1; s < 64; s <<= 1) {
            float Fp = __shfl_up(F, s, 64);
            float Ip = __shfl_up(I, s, 64);
            if (lane >= s) {
                I = fmaf(Ip, F, I);   // use pre-update F
                F *= Fp;
            }
        }
        const float Itot = fmaf(carryI, F, I);   // combine(carry, segment-inclusive)
        float Hex = __shfl_up(Itot, 1, 64);
        if (lane == 0) Hex = carryI;
        Hin[idx] = Hex;
        carryI = __shfl(Itot, 63, 64);
    }
}

__global__ __launch_bounds__(256) void scan_pass3(const u16* __restrict__ ip,
                                                  const u16* __restrict__ fp,
                                                  const float* __restrict__ Hin,
                                                  u16* __restrict__ hout) {
    const int tid = blockIdx.x * 256 + threadIdx.x;  // 262144 threads
    const int d4  = tid & 255;
    const int c   = (tid >> 8) & (NC - 1);
    const int b   = tid >> 16;
    size_t base = ((size_t)(b * TT + c * CT) << 10) + (size_t)d4 * 4;
    const size_t o = (((size_t)(b * NC + c)) << 10) + (size_t)d4 * 4;
    float4 hv = *(const float4*)(Hin + o);
    float h[4] = {hv.x, hv.y, hv.z, hv.w};
#pragma unroll
    for (int t = 0; t < CT; t++) {
        ushort4 fu = *(const ushort4*)(fp + base);
        ushort4 iu = *(const ushort4*)(ip + base);
        const u16 fa[4] = {fu.x, fu.y, fu.z, fu.w};
        const u16 ia[4] = {iu.x, iu.y, iu.z, iu.w};
        ushort4 ou;
        u16 oa[4];
#pragma unroll
        for (int j = 0; j < 4; j++) {
            float f  = sigm(bf2f(fa[j]));
            float iv = bf2f(ia[j]);
            float v  = iv * sigm(iv) * (1.f - f);
            h[j] = fmaf(f, h[j], v);
            oa[j] = f2bf(h[j]);
        }
        ou.x = oa[0]; ou.y = oa[1]; ou.z = oa[2]; ou.w = oa[3];
        *(ushort4*)(hout + base) = ou;
        base += DD;
    }
}

// ---------------------------------------------------------------- RMSNorm * swish(g)
// r0-proven 16384-block version (R6 A/B: the LDS-fused variant cost ~30us — 1 wave/SIMD).
// hin and oout alias (in-place): all h reads happen before the barrier, writes after.
__global__ __launch_bounds__(256) void rmsnorm_gate(const u16* hin,
                                                    const u16* __restrict__ g,
                                                    const float* __restrict__ w,
                                                    u16* oout) {
    const int row = blockIdx.x;
    const int t = threadIdx.x;
    const size_t base = ((size_t)row << 10) + t * 4;
    ushort4 hu = *(const ushort4*)(hin + base);
    float h0 = bf2f(hu.x), h1 = bf2f(hu.y), h2 = bf2f(hu.z), h3 = bf2f(hu.w);
    float ss = h0 * h0 + h1 * h1 + h2 * h2 + h3 * h3;
#pragma unroll
    for (int o = 32; o > 0; o >>= 1) ss += __shfl_down(ss, o);
    __shared__ float red[4];
    if ((t & 63) == 0) red[t >> 6] = ss;
    __syncthreads();
    const float tot = red[0] + red[1] + red[2] + red[3];
    const float rms = rsqrtf(tot * (1.f / 1024.f) + 1e-5f);
    ushort4 gu = *(const ushort4*)(g + base);
    float g0 = bf2f(gu.x), g1 = bf2f(gu.y), g2 = bf2f(gu.z), g3 = bf2f(gu.w);
    float4 wv = *(const float4*)(w + (size_t)t * 4);
    ushort4 ou;
    ou.x = f2bf(h0 * rms * wv.x * g0 * sigm(g0));
    ou.y = f2bf(h1 * rms * wv.y * g1 * sigm(g1));
    ou.z = f2bf(h2 * rms * wv.z * g2 * sigm(g2));
    ou.w = f2bf(h3 * rms * wv.w * g3 * sigm(g3));
    *(ushort4*)(oout + base) = ou;
}

// ---------------------------------------------------------------- launch
extern "C" void kernel_launch(void* const* d_in, const int* in_sizes, int n_in,
                              void* d_out, int out_size, void* d_ws, size_t ws_size,
                              hipStream_t stream) {
    const float* x  = (const float*)d_in[0];
    const float* Wi = (const float*)d_in[1];
    const float* Wf = (const float*)d_in[2];
    const float* Wg = (const float*)d_in[3];
    const float* Wo = (const float*)d_in[4];
    const float* nw = (const float*)d_in[5];
    float* out = (float*)d_out;

    const size_t MB = 1ull << 20;
    char* ws = (char*)d_ws;
    u16*   xo  = (u16*)(ws);              // 32MB: x_bf16, later h_bf16 then o_bf16
    u16*   Wb  = (u16*)(ws + 32 * MB);    // 8MB: [Wi;Wf;Wg;Wo] bf16, K-major rows
    u16*   Pi  = (u16*)(ws + 40 * MB);    // 32MB: i_pre bf16
    u16*   Pf  = (u16*)(ws + 72 * MB);    // 32MB: f_pre bf16
    // chunk side-arrays (4MB each at NC=256) live in the UNUSED upper half of d_out
    // (g occupies d_out[0:32MB]; out is only written by the final GEMM, after all
    //  side-array consumers have run) -> workspace footprint unchanged vs r0.
    float* Fc  = (float*)((char*)d_out + 32 * MB);  // 4MB
    float* Ic  = Fc + BB * NC * DD;                 // 4MB
    float* Hin = Ic + BB * NC * DD;                 // 4MB (ends at d_out+44MB < 64MB)
    u16*   g   = (u16*)d_out;             // g plane (bf16) parked in d_out until final GEMM

    conv_x_kernel<<<16384, 256, 0, stream>>>(x, xo);
    conv_w4_kernel<<<4096, 256, 0, stream>>>(Wi, Wf, Wg, Wo, Wb);
    // i_pre / f_pre / g in one GEMM: N=3072
    gemm_bf16_bt<u16><<<dim3(24, 128), 256, 0, stream>>>(xo, Wb, 1024, Pi, Pf, g);
    scan_pass1<<<1024, 256, 0, stream>>>(Pi, Pf, Fc, Ic);
    scan_pass2<<<1024, 256, 0, stream>>>(Fc, Ic, Hin);
    scan_pass3<<<1024, 256, 0, stream>>>(Pi, Pf, Hin, xo);
    rmsnorm_gate<<<16384, 256, 0, stream>>>(xo, g, nw, xo);
    // out = o @ Wo^T
    gemm_bf16_bt<float><<<dim3(8, 128), 256, 0, stream>>>(xo, Wb + 3ull * 1024 * 1024, 1024,
                                                          out, out, out);
}